// Round 15
// baseline (252.465 us; speedup 1.0000x reference)
//
#include <hip/hip_runtime.h>

// LSTM B=4096, S=512, INPUT=1, HIDDEN=20 + linear head.
// R14: R13 (cooperative 4-wave block, step split across the CU's 4 SIMDs)
// + second co-resident block per CU to fill the stall.
// R13 counters: wall 760 cyc/step; per-SIMD busy only ~280 (VALUBusy 29%
// incl. trans + 24 MFMA + LDS) -> ~480 cyc/step of act-chain latency, LDS
// round-trip and barrier stagger that 1 wave/SIMD can't overlap.  Changes:
//  - 512 blocks x 8 chains (4096 exact), __launch_bounds__(256,2):
//    2 independent blocks/CU = 2 waves/SIMD with separate barrier domains;
//    one block issues while the other stalls.  Acts/writes masked n<8;
//    MFMA columns n>=8 are zero ballast (MfmaUtil ~3%, irrelevant).
//  - wave-role permutation by blockIdx hash: the heavy dual-unit wave (14
//    trans) lands on a different SIMD for co-resident blocks (avoid
//    stacking both heavy waves on SIMD0).
//  - hrow stride 40 -> 44 halfs (22 words): R13's writes were 8-WAY bank
//    conflicted (all addrs 16B-chunk-aligned + per-wave-constant offset ->
//    only 8 banks; 5.2M conflict cycles).  Stride 22 words spreads n over
//    all even banks -> 2-way (free).  Reads switch to 2xb64 (8B-aligned),
//    same BW-bound cost as b128.
// Layout otherwise identical to R13 (verified absmax 9.77e-4): A row 4Q+r =
// gate r of unit 5Q+m, k-slot s = unit 5q+s (s<5); C col=lane&15,
// row=4*(lane>>4)+reg; x*W_ih+bias via f32 C-operand; head one-step skew
// (R8 pattern) + epilogue.  Roles: w0 m{0,1}, w1 m{2}, w2 m{3}, w3 m{4}+head.

#define BATCH 4096
#define SLEN  512
#define H     20
#define CH    8      // chains per block
#define RS    44     // hrow stride in halfs (22 words: 2-way write banks)
#define LOG2E 1.44269504088896340736f

typedef _Float16 f16x8 __attribute__((ext_vector_type(8)));
typedef _Float16 f16x4 __attribute__((ext_vector_type(4)));
typedef _Float16 h2    __attribute__((ext_vector_type(2)));
typedef float    f32x4 __attribute__((ext_vector_type(4)));

__device__ __forceinline__ float fexp2(float x) { return __builtin_amdgcn_exp2f(x); }
__device__ __forceinline__ float frcp(float x)  { return __builtin_amdgcn_rcpf(x); }

// one unit's activations (R11b/R13-verified): Cv = [i,f,g,o] pre-scaled
#define ACT(Cv, CC, HV) {                                             \
    const float eI = fexp2((Cv)[0]);                                  \
    const float eF = fexp2((Cv)[1]);                                  \
    const float eG = fexp2((Cv)[2]);                                  \
    const float eO = fexp2((Cv)[3]);                                  \
    const float pF = 1.0f + eF;                                       \
    const float P  = (1.0f + eI) * (1.0f + eG);                       \
    const float num = fmaf(CC, P, (1.0f - eG) * pF);                  \
    CC = fmaxf(num * frcp(pF * P), -34.0f);                           \
    const float eC = fexp2(s2 * CC);                                  \
    HV = (1.0f - eC) * frcp((1.0f + eO) * (1.0f + eC));               \
}

__global__ __launch_bounds__(256, 2) void lstm_fused(
    const float* __restrict__ x,      // [B, S, 1]
    const float* __restrict__ W_ih,   // [80, 1]
    const float* __restrict__ W_hh,   // [80, 20]
    const float* __restrict__ b_ih,   // [80]
    const float* __restrict__ b_hh,   // [80]
    const float* __restrict__ W_lin,  // [1, 20]
    const float* __restrict__ b_lin,  // [1]
    float* __restrict__ out)          // [B, S, 1]
{
    __shared__ __align__(16) _Float16 hrow[2][16][RS];

    const int tid  = threadIdx.x;
    const int wv   = tid >> 6;          // wave 0..3
    const int lane = tid & 63;
    const int q    = lane >> 4;         // k-group / unit-block 0..3
    const int n    = lane & 15;         // mfma column; chains live in n<8
    const bool nv  = (n < CH);
    const long b   = (long)blockIdx.x * CH + (n & 7);   // clamped (dup for n>=8)

    const float s1 = -LOG2E;            // sigmoid pre-scale
    const float s2 = -2.0f * LOG2E;     // tanh pre-scale

    // wave role, permuted per block so co-resident heavy waves don't stack
    const int  wr   = (wv + ((blockIdx.x ^ (blockIdx.x >> 8)) & 3)) & 3;
    const int  m0   = (wr == 0) ? 0 : (wr + 1);   // owned mfma: w0:{0,1} w1:2 w2:3 w3:4
    const bool dual = (wr == 0);

    // ---- A fragments (f16): row n -> gate gA of unit uA+m; k-slot s =
    // unit 5q+s (s<5), slots 5-7 zero ----
    const int gA = n & 3;
    const int uA = (n >> 2) * 5;
    const float scA = (gA == 2) ? s2 : s1;   // torch gate order i,f,g,o
    f16x8 am0, am1;
    {
        const int r0 = gA * H + uA + m0;
        const int r1 = gA * H + uA + 1;      // m=1 (used only by dual wave)
#pragma unroll
        for (int s = 0; s < 8; ++s) {
            am0[s] = (_Float16)((s < 5) ? scA * W_hh[r0 * H + 5 * q + s] : 0.0f);
            am1[s] = (_Float16)((s < 5) ? scA * W_hh[r1 * H + 5 * q + s] : 0.0f);
        }
    }
    // head A (role 3): row 0 = W_lin; b_lin via C-input
    f16x8 ah;
#pragma unroll
    for (int s = 0; s < 8; ++s)
        ah[s] = (_Float16)((n == 0 && s < 5) ? W_lin[5 * q + s] : 0.0f);
    const f32x4 chi = {(q == 0) ? b_lin[0] : 0.0f, 0.0f, 0.0f, 0.0f};

    // ---- f32 C-init constants for owned units ----
    f32x4 xw0, bb0, xw1, bb1;
#pragma unroll
    for (int r = 0; r < 4; ++r) {
        const float sc = (r == 2) ? s2 : s1;
        const int r0 = r * H + 5 * q + m0;
        const int r1 = r * H + 5 * q + 1;
        xw0[r] = sc * W_ih[r0];  bb0[r] = sc * (b_ih[r0] + b_hh[r0]);
        xw1[r] = sc * W_ih[r1];  bb1[r] = sc * (b_ih[r1] + b_hh[r1]);
    }

    const float* xb = x + b * SLEN;
    float*       ob = out + b * SLEN;

    // zero both h buffers (h(-1)=0 in parity 1; rows n>=8 stay 0 forever)
    for (int i = tid; i < 2 * 16 * RS / 2; i += 256) ((unsigned*)hrow)[i] = 0u;
    __syncthreads();

    float cc0 = 0.0f, cc1 = 0.0f;   // c state of owned units
    f32x4 ya;                       // role3: y quad (one-step skew)
    f32x4 xc = *(const f32x4*)xb;   // current x quad

#define STEP(p)                                                            \
    {                                                                      \
        const _Float16* hp_ = &hrow[((p) & 1) ^ 1][n][8 * q];              \
        const f16x4 lo_ = *(const f16x4*)hp_;                              \
        const f16x4 hi_ = *(const f16x4*)(hp_ + 4);                        \
        const f16x8 bf = __builtin_shufflevector(lo_, hi_,                 \
                                                 0, 1, 2, 3, 4, 5, 6, 7); \
        if (wr == 3) {                                                     \
            const f32x4 Ch =                                               \
                __builtin_amdgcn_mfma_f32_16x16x32_f16(ah, bf, chi, 0, 0, 0); \
            const float yv = Ch[0];            /* y(t-1), t = 4k+p */      \
            if ((p) == 0) {                                                \
                ya[3] = yv;                                                \
                if (k > 0 && lane < CH) *(f32x4*)(ob + 4 * k - 4) = ya;    \
            } else if ((p) == 1) ya[0] = yv;                               \
            else if ((p) == 2) ya[1] = yv;                                 \
            else ya[2] = yv;                                               \
        }                                                                  \
        const float xt = xc[(p)];                                          \
        f32x4 ci0;                                                         \
        ci0[0] = fmaf(xt, xw0[0], bb0[0]);                                 \
        ci0[1] = fmaf(xt, xw0[1], bb0[1]);                                 \
        ci0[2] = fmaf(xt, xw0[2], bb0[2]);                                 \
        ci0[3] = fmaf(xt, xw0[3], bb0[3]);                                 \
        f32x4 C0 = __builtin_amdgcn_mfma_f32_16x16x32_f16(am0, bf, ci0, 0, 0, 0); \
        float h0v;                                                         \
        ACT(C0, cc0, h0v);                                                 \
        if (dual) {                                                        \
            f32x4 ci1;                                                     \
            ci1[0] = fmaf(xt, xw1[0], bb1[0]);                             \
            ci1[1] = fmaf(xt, xw1[1], bb1[1]);                             \
            ci1[2] = fmaf(xt, xw1[2], bb1[2]);                             \
            ci1[3] = fmaf(xt, xw1[3], bb1[3]);                             \
            f32x4 C1 = __builtin_amdgcn_mfma_f32_16x16x32_f16(am1, bf, ci1, 0, 0, 0); \
            float h1v;                                                     \
            ACT(C1, cc1, h1v);                                             \
            if (nv) {                                                      \
                h2 pr_; pr_.x = (_Float16)h0v; pr_.y = (_Float16)h1v;      \
                *(h2*)&hrow[(p) & 1][n][8 * q] = pr_;   /* units m=0,1 */  \
            }                                                              \
        } else if (nv) {                                                   \
            hrow[(p) & 1][n][8 * q + m0] = (_Float16)h0v;                  \
        }                                                                  \
        __syncthreads();                                                   \
    }

#pragma unroll 1
    for (int k = 0; k < 128; ++k) {
        const int t0 = 4 * k;
        const int tn = (t0 + 4 < SLEN) ? t0 + 4 : SLEN - 4;   // clamp
        const f32x4 xn = *(const f32x4*)(xb + tn);            // prefetch

        STEP(0) STEP(1) STEP(2) STEP(3)

        xc = xn;
    }
#undef STEP

    // epilogue: y(511) from h(511) (parity 1, published by last barrier)
    if (wr == 3) {
        const _Float16* hp_ = &hrow[1][n][8 * q];
        const f16x4 lo_ = *(const f16x4*)hp_;
        const f16x4 hi_ = *(const f16x4*)(hp_ + 4);
        const f16x8 bf = __builtin_shufflevector(lo_, hi_, 0, 1, 2, 3, 4, 5, 6, 7);
        const f32x4 Ch = __builtin_amdgcn_mfma_f32_16x16x32_f16(ah, bf, chi, 0, 0, 0);
        ya[3] = Ch[0];
        if (lane < CH) *(f32x4*)(ob + SLEN - 4) = ya;
    }
}

extern "C" void kernel_launch(void* const* d_in, const int* in_sizes, int n_in,
                              void* d_out, int out_size, void* d_ws, size_t ws_size,
                              hipStream_t stream) {
    const float* x     = (const float*)d_in[0];
    const float* W_ih  = (const float*)d_in[1];
    const float* W_hh  = (const float*)d_in[2];
    const float* b_ih  = (const float*)d_in[3];
    const float* b_hh  = (const float*)d_in[4];
    const float* W_lin = (const float*)d_in[5];
    const float* b_lin = (const float*)d_in[6];
    float* out = (float*)d_out;

    const int nblocks = BATCH / CH;   // 512 blocks x 4 waves: 2 blocks/CU
    lstm_fused<<<nblocks, 256, 0, stream>>>(x, W_ih, W_hh, b_ih, b_hh,
                                            W_lin, b_lin, out);
}

// Round 17
// 243.544 us; speedup vs baseline: 1.0366x; 1.0366x over previous
//
#include <hip/hip_runtime.h>

// LSTM B=4096, S=512, INPUT=1, HIDDEN=20 + linear head.
// R15b: identical to R15 (container infra failed twice; no kernel signal —
// same signature as R2/R9, both of which ran clean on resubmit).
// Design: two DENSE 16-chain groups per 512-thread block (8 waves), 128
// blocks.  R14 post-mortem: ACT trans ops are wave-wide regardless of
// column masking -> act density (64 active lanes/ACT) is the invariant.
// R13's wall (760 cyc/step) = max-wave issue (~300) PLUS serial latency
// (~450): with 1 wave/SIMD nothing fills the read/MFMA/act-chain stalls.
// Here waves k and k+4 share SIMD k, carry INDEPENDENT 16-chain groups
// (separate hrow, separate c/h state), and meet at the same block barrier:
// the SIMD interleaves the two streams, so group B's issue fills group A's
// latency.  Per-chain trans cost optimal (no ballast).  128 blocks = half
// the CUs -- per-CU throughput should more than double.
//  - roles rotated between groups: group0 dual-ACT wave on SIMD0, group1's
//    on SIMD3 (SIMD trans load 21/14/14/21 instead of 28 worst-case).
//  - RS=44 stride kept from R14 (bank conflicts 5.2M->2.1M), 2xb64 reads.
// Layout per group identical to R13 (verified absmax 9.77e-4): A row 4Q+r =
// gate r of unit 5Q+m, k-slot s = unit 5q+s (s<5); C col=lane&15,
// row=4*(lane>>4)+reg; x*W_ih+bias via f32 C-operand; head one-step skew +
// epilogue.  Roles: wr0 m{0,1}, wr1 m{2}, wr2 m{3}, wr3 m{4}+head.

#define BATCH 4096
#define SLEN  512
#define H     20
#define RS    44     // hrow stride in halfs (22 words: spread write banks)
#define LOG2E 1.44269504088896340736f

typedef _Float16 f16x8 __attribute__((ext_vector_type(8)));
typedef _Float16 f16x4 __attribute__((ext_vector_type(4)));
typedef _Float16 h2    __attribute__((ext_vector_type(2)));
typedef float    f32x4 __attribute__((ext_vector_type(4)));

__device__ __forceinline__ float fexp2(float x) { return __builtin_amdgcn_exp2f(x); }
__device__ __forceinline__ float frcp(float x)  { return __builtin_amdgcn_rcpf(x); }

// one unit's activations (R11b/R13-verified): Cv = [i,f,g,o] pre-scaled
#define ACT(Cv, CC, HV) {                                             \
    const float eI = fexp2((Cv)[0]);                                  \
    const float eF = fexp2((Cv)[1]);                                  \
    const float eG = fexp2((Cv)[2]);                                  \
    const float eO = fexp2((Cv)[3]);                                  \
    const float pF = 1.0f + eF;                                       \
    const float P  = (1.0f + eI) * (1.0f + eG);                       \
    const float num = fmaf(CC, P, (1.0f - eG) * pF);                  \
    CC = fmaxf(num * frcp(pF * P), -34.0f);                           \
    const float eC = fexp2(s2 * CC);                                  \
    HV = (1.0f - eC) * frcp((1.0f + eO) * (1.0f + eC));               \
}

__global__ __launch_bounds__(512, 1) void lstm_fused(
    const float* __restrict__ x,      // [B, S, 1]
    const float* __restrict__ W_ih,   // [80, 1]
    const float* __restrict__ W_hh,   // [80, 20]
    const float* __restrict__ b_ih,   // [80]
    const float* __restrict__ b_hh,   // [80]
    const float* __restrict__ W_lin,  // [1, 20]
    const float* __restrict__ b_lin,  // [1]
    float* __restrict__ out)          // [B, S, 1]
{
    __shared__ __align__(16) _Float16 hrow[2][2][16][RS];  // [group][parity][chain][slots]

    const int tid  = threadIdx.x;
    const int wv   = tid >> 6;          // wave 0..7
    const int g    = wv >> 2;           // chain group 0/1
    const int wg   = wv & 3;            // within-group wave (SIMD id = wg)
    const int lane = tid & 63;
    const int q    = lane >> 4;         // k-group / unit-block 0..3
    const int n    = lane & 15;         // chain column (DENSE: all 16 real)
    const long b   = (long)blockIdx.x * 32 + g * 16 + n;   // 128*32 = 4096

    const float s1 = -LOG2E;            // sigmoid pre-scale
    const float s2 = -2.0f * LOG2E;     // tanh pre-scale

    // role: group0 dual wave on SIMD0, group1 dual wave on SIMD3
    const int  wr   = (g == 0) ? wg : ((wg + 1) & 3);
    const int  m0   = (wr == 0) ? 0 : (wr + 1);   // owned mfma
    const bool dual = (wr == 0);

    // ---- A fragments (f16): row n -> gate gA of unit uA+m; k-slot s =
    // unit 5q+s (s<5), slots 5-7 zero ----
    const int gA = n & 3;
    const int uA = (n >> 2) * 5;
    const float scA = (gA == 2) ? s2 : s1;   // torch gate order i,f,g,o
    f16x8 am0, am1;
    {
        const int r0 = gA * H + uA + m0;
        const int r1 = gA * H + uA + 1;      // m=1 (used only by dual wave)
#pragma unroll
        for (int s = 0; s < 8; ++s) {
            am0[s] = (_Float16)((s < 5) ? scA * W_hh[r0 * H + 5 * q + s] : 0.0f);
            am1[s] = (_Float16)((s < 5) ? scA * W_hh[r1 * H + 5 * q + s] : 0.0f);
        }
    }
    // head A (role 3): row 0 = W_lin; b_lin via C-input
    f16x8 ah;
#pragma unroll
    for (int s = 0; s < 8; ++s)
        ah[s] = (_Float16)((n == 0 && s < 5) ? W_lin[5 * q + s] : 0.0f);
    const f32x4 chi = {(q == 0) ? b_lin[0] : 0.0f, 0.0f, 0.0f, 0.0f};

    // ---- f32 C-init constants for owned units ----
    f32x4 xw0, bb0, xw1, bb1;
#pragma unroll
    for (int r = 0; r < 4; ++r) {
        const float sc = (r == 2) ? s2 : s1;
        const int r0 = r * H + 5 * q + m0;
        const int r1 = r * H + 5 * q + 1;
        xw0[r] = sc * W_ih[r0];  bb0[r] = sc * (b_ih[r0] + b_hh[r0]);
        xw1[r] = sc * W_ih[r1];  bb1[r] = sc * (b_ih[r1] + b_hh[r1]);
    }

    const float* xb = x + b * SLEN;
    float*       ob = out + b * SLEN;

    // zero both groups' h buffers (h(-1)=0 in parity 1)
    for (int i = tid; i < 2 * 2 * 16 * RS / 2; i += 512) ((unsigned*)hrow)[i] = 0u;
    __syncthreads();

    float cc0 = 0.0f, cc1 = 0.0f;   // c state of owned units
    f32x4 ya;                       // role3: y quad (one-step skew)
    f32x4 xc = *(const f32x4*)xb;   // current x quad

#define STEP(p)                                                            \
    {                                                                      \
        const _Float16* hp_ = &hrow[g][((p) & 1) ^ 1][n][8 * q];           \
        const f16x4 lo_ = *(const f16x4*)hp_;                              \
        const f16x4 hi_ = *(const f16x4*)(hp_ + 4);                        \
        const f16x8 bf = __builtin_shufflevector(lo_, hi_,                 \
                                                 0, 1, 2, 3, 4, 5, 6, 7); \
        if (wr == 3) {                                                     \
            const f32x4 Ch =                                               \
                __builtin_amdgcn_mfma_f32_16x16x32_f16(ah, bf, chi, 0, 0, 0); \
            const float yv = Ch[0];            /* y(t-1), t = 4k+p */      \
            if ((p) == 0) {                                                \
                ya[3] = yv;                                                \
                if (k > 0 && lane < 16) *(f32x4*)(ob + 4 * k - 4) = ya;    \
            } else if ((p) == 1) ya[0] = yv;                               \
            else if ((p) == 2) ya[1] = yv;                                 \
            else ya[2] = yv;                                               \
        }                                                                  \
        const float xt = xc[(p)];                                          \
        f32x4 ci0;                                                         \
        ci0[0] = fmaf(xt, xw0[0], bb0[0]);                                 \
        ci0[1] = fmaf(xt, xw0[1], bb0[1]);                                 \
        ci0[2] = fmaf(xt, xw0[2], bb0[2]);                                 \
        ci0[3] = fmaf(xt, xw0[3], bb0[3]);                                 \
        f32x4 C0 = __builtin_amdgcn_mfma_f32_16x16x32_f16(am0, bf, ci0, 0, 0, 0); \
        float h0v;                                                         \
        ACT(C0, cc0, h0v);                                                 \
        if (dual) {                                                        \
            f32x4 ci1;                                                     \
            ci1[0] = fmaf(xt, xw1[0], bb1[0]);                             \
            ci1[1] = fmaf(xt, xw1[1], bb1[1]);                             \
            ci1[2] = fmaf(xt, xw1[2], bb1[2]);                             \
            ci1[3] = fmaf(xt, xw1[3], bb1[3]);                             \
            f32x4 C1 = __builtin_amdgcn_mfma_f32_16x16x32_f16(am1, bf, ci1, 0, 0, 0); \
            float h1v;                                                     \
            ACT(C1, cc1, h1v);                                             \
            h2 pr_; pr_.x = (_Float16)h0v; pr_.y = (_Float16)h1v;          \
            *(h2*)&hrow[g][(p) & 1][n][8 * q] = pr_;      /* units m=0,1 */ \
        } else {                                                           \
            hrow[g][(p) & 1][n][8 * q + m0] = (_Float16)h0v;               \
        }                                                                  \
        __syncthreads();                                                   \
    }

#pragma unroll 1
    for (int k = 0; k < 128; ++k) {
        const int t0 = 4 * k;
        const int tn = (t0 + 4 < SLEN) ? t0 + 4 : SLEN - 4;   // clamp
        const f32x4 xn = *(const f32x4*)(xb + tn);            // prefetch

        STEP(0) STEP(1) STEP(2) STEP(3)

        xc = xn;
    }
#undef STEP

    // epilogue: y(511) from h(511) (parity 1, published by last barrier)
    if (wr == 3) {
        const _Float16* hp_ = &hrow[g][1][n][8 * q];
        const f16x4 lo_ = *(const f16x4*)hp_;
        const f16x4 hi_ = *(const f16x4*)(hp_ + 4);
        const f16x8 bf = __builtin_shufflevector(lo_, hi_, 0, 1, 2, 3, 4, 5, 6, 7);
        const f32x4 Ch = __builtin_amdgcn_mfma_f32_16x16x32_f16(ah, bf, chi, 0, 0, 0);
        ya[3] = Ch[0];
        if (lane < 16) *(f32x4*)(ob + SLEN - 4) = ya;
    }
}

extern "C" void kernel_launch(void* const* d_in, const int* in_sizes, int n_in,
                              void* d_out, int out_size, void* d_ws, size_t ws_size,
                              hipStream_t stream) {
    const float* x     = (const float*)d_in[0];
    const float* W_ih  = (const float*)d_in[1];
    const float* W_hh  = (const float*)d_in[2];
    const float* b_ih  = (const float*)d_in[3];
    const float* b_hh  = (const float*)d_in[4];
    const float* W_lin = (const float*)d_in[5];
    const float* b_lin = (const float*)d_in[6];
    float* out = (float*)d_out;

    const int nblocks = BATCH / 32;   // 128 blocks x 8 waves (2 dense groups)
    lstm_fused<<<nblocks, 512, 0, stream>>>(x, W_ih, W_hh, b_ih, b_hh,
                                            W_lin, b_lin, out);
}

// Round 18
// 182.072 us; speedup vs baseline: 1.3866x; 1.3376x over previous
//
#include <hip/hip_runtime.h>

// LSTM B=4096, S=512, INPUT=1, HIDDEN=20 + linear head.
// R16: fine-grained role split — ONE ACT per wave, 6 waves, full chip.
// Model (fits R13/R14/R15b): wall ~= max-per-SIMD trans issue (16 cyc/op,
// trans pipe is per-SIMD) + ~450 residual (read 120 + mfma + act latency +
// barrier).  R13's w0 owned TWO ACTs (28 trans = 448 cyc) -> 760.  R15b's
// worst SIMD 21 trans -> 860.  Fix: 256 blocks x 384 thr (16 chains/block,
// full chip); waves 0-4 own one gate-mfma m + one dense ACT (7 trans) each;
// wave 5 owns the head mfma + y store.  Round-robin wave->SIMD: SIMD0 gets
// m0+m4, SIMD1 m1+head, SIMD2 m2, SIMD3 m3 -> worst SIMD = 14 trans but as
// TWO independent streams whose latencies mutually hide (R15b mechanism,
// now intra-CU at full chip).  Expected ~500-580 cyc/step vs R13's 760.
// Numerics identical to R13 (verified absmax 9.77e-4): A row 4Q+r = gate r
// of unit 5Q+m, k-slot s = unit 5q+s (s<5); C col=lane&15,
// row=4*(lane>>4)+reg; x*W_ih+bias via f32 C-operand; fused-reciprocal ACT
// (5 exp2 + 2 rcp), c >= -34; head one-step skew + epilogue; RS=44 stride
// (bank spread), 2xb64 h reads.

#define BATCH 4096
#define SLEN  512
#define H     20
#define RS    44     // hrow stride in halfs (22 words: spread write banks)
#define LOG2E 1.44269504088896340736f

typedef _Float16 f16x8 __attribute__((ext_vector_type(8)));
typedef _Float16 f16x4 __attribute__((ext_vector_type(4)));
typedef float    f32x4 __attribute__((ext_vector_type(4)));

__device__ __forceinline__ float fexp2(float x) { return __builtin_amdgcn_exp2f(x); }
__device__ __forceinline__ float frcp(float x)  { return __builtin_amdgcn_rcpf(x); }

// one unit's activations (R11b/R13-verified): Cv = [i,f,g,o] pre-scaled
#define ACT(Cv, CC, HV) {                                             \
    const float eI = fexp2((Cv)[0]);                                  \
    const float eF = fexp2((Cv)[1]);                                  \
    const float eG = fexp2((Cv)[2]);                                  \
    const float eO = fexp2((Cv)[3]);                                  \
    const float pF = 1.0f + eF;                                       \
    const float P  = (1.0f + eI) * (1.0f + eG);                       \
    const float num = fmaf(CC, P, (1.0f - eG) * pF);                  \
    CC = fmaxf(num * frcp(pF * P), -34.0f);                           \
    const float eC = fexp2(s2 * CC);                                  \
    HV = (1.0f - eC) * frcp((1.0f + eO) * (1.0f + eC));               \
}

__global__ __launch_bounds__(384, 1) void lstm_fused(
    const float* __restrict__ x,      // [B, S, 1]
    const float* __restrict__ W_ih,   // [80, 1]
    const float* __restrict__ W_hh,   // [80, 20]
    const float* __restrict__ b_ih,   // [80]
    const float* __restrict__ b_hh,   // [80]
    const float* __restrict__ W_lin,  // [1, 20]
    const float* __restrict__ b_lin,  // [1]
    float* __restrict__ out)          // [B, S, 1]
{
    __shared__ __align__(16) _Float16 hrow[2][16][RS];   // [parity][chain][slots]

    const int tid  = threadIdx.x;
    const int wv   = tid >> 6;          // wave 0..5
    const int lane = tid & 63;
    const int q    = lane >> 4;         // k-group / unit-block 0..3
    const int n    = lane & 15;         // chain column (dense)
    const long b   = (long)blockIdx.x * 16 + n;   // 256*16 = 4096 exact

    const float s1 = -LOG2E;            // sigmoid pre-scale
    const float s2 = -2.0f * LOG2E;     // tanh pre-scale

    const bool isgate = (wv < 5);       // waves 0..4: gate mfma m=wv + ACT
    const bool ishead = (wv == 5);      // wave 5: head mfma + y store
    const int  m     = isgate ? wv : 0;

    // ---- A fragment (f16): row n -> gate gA of unit uA+m; k-slot s =
    // unit 5q+s (s<5), slots 5-7 zero ----
    const int gA = n & 3;
    const int uA = (n >> 2) * 5;
    const float scA = (gA == 2) ? s2 : s1;   // torch gate order i,f,g,o
    f16x8 am;
    {
        const int row = gA * H + uA + m;
#pragma unroll
        for (int s = 0; s < 8; ++s)
            am[s] = (_Float16)((s < 5) ? scA * W_hh[row * H + 5 * q + s] : 0.0f);
    }
    // head A: row 0 = W_lin; b_lin via C-input
    f16x8 ah;
#pragma unroll
    for (int s = 0; s < 8; ++s)
        ah[s] = (_Float16)((n == 0 && s < 5) ? W_lin[5 * q + s] : 0.0f);
    const f32x4 chi = {(q == 0) ? b_lin[0] : 0.0f, 0.0f, 0.0f, 0.0f};

    // ---- f32 C-init constants for the owned unit (gate waves) ----
    f32x4 xw, bb;
#pragma unroll
    for (int r = 0; r < 4; ++r) {
        const float sc = (r == 2) ? s2 : s1;
        const int row = r * H + 5 * q + m;
        xw[r] = sc * W_ih[row];
        bb[r] = sc * (b_ih[row] + b_hh[row]);
    }

    const float* xb = x + b * SLEN;
    float*       ob = out + b * SLEN;

    // zero both parities (h(-1)=0 in parity 1): 2*16*RS halfs = 704 words
    for (int i = tid; i < 2 * 16 * RS / 2; i += 384) ((unsigned*)hrow)[i] = 0u;
    __syncthreads();

    float cc = 0.0f;                 // c state of owned unit (gate waves)
    f32x4 ya;                        // head wave: y quad (one-step skew)
    f32x4 xc = *(const f32x4*)xb;    // current x quad

#define STEP(p)                                                            \
    {                                                                      \
        f16x8 bf;                                                          \
        {                                                                  \
            const _Float16* hp_ = &hrow[((p) & 1) ^ 1][n][8 * q];          \
            const f16x4 lo_ = *(const f16x4*)hp_;                          \
            const f16x4 hi_ = *(const f16x4*)(hp_ + 4);                    \
            bf = __builtin_shufflevector(lo_, hi_, 0, 1, 2, 3, 4, 5, 6, 7); \
        }                                                                  \
        if (ishead) {                                                      \
            const f32x4 Ch =                                               \
                __builtin_amdgcn_mfma_f32_16x16x32_f16(ah, bf, chi, 0, 0, 0); \
            const float yv = Ch[0];            /* y(t-1), t = 4k+p */      \
            if ((p) == 0) {                                                \
                ya[3] = yv;                                                \
                if (k > 0 && lane < 16) *(f32x4*)(ob + 4 * k - 4) = ya;    \
            } else if ((p) == 1) ya[0] = yv;                               \
            else if ((p) == 2) ya[1] = yv;                                 \
            else ya[2] = yv;                                               \
        }                                                                  \
        if (isgate) {                                                      \
            const float xt = xc[(p)];                                      \
            f32x4 ci;                                                      \
            ci[0] = fmaf(xt, xw[0], bb[0]);                                \
            ci[1] = fmaf(xt, xw[1], bb[1]);                                \
            ci[2] = fmaf(xt, xw[2], bb[2]);                                \
            ci[3] = fmaf(xt, xw[3], bb[3]);                                \
            f32x4 C0 = __builtin_amdgcn_mfma_f32_16x16x32_f16(am, bf, ci, 0, 0, 0); \
            float hv;                                                      \
            ACT(C0, cc, hv);                                               \
            hrow[(p) & 1][n][8 * q + m] = (_Float16)hv;                    \
        }                                                                  \
        __syncthreads();                                                   \
    }

#pragma unroll 1
    for (int k = 0; k < 128; ++k) {
        const int t0 = 4 * k;
        const int tn = (t0 + 4 < SLEN) ? t0 + 4 : SLEN - 4;   // clamp
        const f32x4 xn = *(const f32x4*)(xb + tn);            // prefetch

        STEP(0) STEP(1) STEP(2) STEP(3)

        xc = xn;
    }
#undef STEP

    // epilogue: y(511) from h(511) (parity 1, published by last barrier)
    if (ishead) {
        const _Float16* hp_ = &hrow[1][n][8 * q];
        const f16x4 lo_ = *(const f16x4*)hp_;
        const f16x4 hi_ = *(const f16x4*)(hp_ + 4);
        const f16x8 bf = __builtin_shufflevector(lo_, hi_, 0, 1, 2, 3, 4, 5, 6, 7);
        const f32x4 Ch = __builtin_amdgcn_mfma_f32_16x16x32_f16(ah, bf, chi, 0, 0, 0);
        ya[3] = Ch[0];
        if (lane < 16) *(f32x4*)(ob + SLEN - 4) = ya;
    }
}

extern "C" void kernel_launch(void* const* d_in, const int* in_sizes, int n_in,
                              void* d_out, int out_size, void* d_ws, size_t ws_size,
                              hipStream_t stream) {
    const float* x     = (const float*)d_in[0];
    const float* W_ih  = (const float*)d_in[1];
    const float* W_hh  = (const float*)d_in[2];
    const float* b_ih  = (const float*)d_in[3];
    const float* b_hh  = (const float*)d_in[4];
    const float* W_lin = (const float*)d_in[5];
    const float* b_lin = (const float*)d_in[6];
    float* out = (float*)d_out;

    const int nblocks = BATCH / 16;   // 256 blocks x 6 waves: full chip
    lstm_fused<<<nblocks, 384, 0, stream>>>(x, W_ih, W_hh, b_ih, b_hh,
                                            W_lin, b_lin, out);
}